// Round 3
// baseline (333.594 us; speedup 1.0000x reference)
//
#include <hip/hip_runtime.h>
#include <hip/hip_bf16.h>

typedef _Float16 half8 __attribute__((ext_vector_type(8)));
typedef _Float16 half4v __attribute__((ext_vector_type(4)));
typedef float floatx4 __attribute__((ext_vector_type(4)));
typedef float floatx16 __attribute__((ext_vector_type(16)));

// ---------------------------------------------------------------------------
// R19: geometry = R18 (128x64 wave tile, 4m x 2n, BM=128, 4-wave blocks,
// 2 blocks/CU = 2 waves/SIMD from different blocks). Schedule rebuilt:
//
// R18 post-mortem: copy-based prefetch (wc=wn/ac=an) forced a full
// s_waitcnt vmcnt(0) lgkmcnt(0) + ~24 v_mov per kstep (the anti-pattern of
// counted-vmcnt) -> ~670 cy/kstep stall above the 512-cy matrix floor,
// VALUBusy 34%, MfmaUtil 45%. R19 ports R16's PROVEN no-copy 2-deep W ring
// (alternating register sets, waits become per-use counted + staggered ~2-4
// ksteps ahead of use) to the 128x64 tile, collapses A addressing to ONE
// base VGPR + 16-bit immediate ds offsets (s*4096 + mi*512 B <= 63 KiB),
// templates the x-vs-act routing (no per-read runtime select in L1/L5),
// wraps MFMA clusters in s_setprio, and converts acc->fp16 BEFORE the
// in-place barrier (shrinks the serialized post-barrier section).
//
// Act layout: chunk-major, 128-row chunks:
//   off(row, col) = (col>>3)*1024 + row*8 + (col&7)   [halfs]
// LDS: act 128x256 fp16 (64 KiB, in-place) + x 128x48 (12 KiB) = 76 KiB.
// __launch_bounds__(256,2) -> 256-reg cap (acc 128 + ~90 arch regs).
// ---------------------------------------------------------------------------
__device__ __forceinline__ int cmaj(int row, int col) {
    return ((col >> 3) << 10) + (row << 3) + (col & 7);
}

// ---------------------------------------------------------------------------
// Weight pre-pack (unchanged, proven R5-R18): fp32 (K,N) row-major -> fp16
// fragment order; lane L holds W[kt*16 + 8*(L>>5) + j][nt*32 + (L&31)].
// Fed to the MFMA *A* operand so D = C^T. K zero-padded: L1 39->64 (KT=4),
// L5 295->320 (KT=20), others 256 (KT=16). L9 N 4->32. Tile starts (1KB):
// {0,32,160,288,416,576,704,832,960}, total 976 tiles = 999424 B in d_ws.
// ---------------------------------------------------------------------------
__global__ void pack_w32(const float* __restrict__ w1, const float* __restrict__ w2,
                         const float* __restrict__ w3, const float* __restrict__ w4,
                         const float* __restrict__ w5, const float* __restrict__ w6,
                         const float* __restrict__ w7, const float* __restrict__ w8,
                         const float* __restrict__ w9, _Float16* __restrict__ dst) {
    const int tileStart[10] = {0, 32, 160, 288, 416, 576, 704, 832, 960, 976};
    const int Ks[9] = {39, 256, 256, 256, 295, 256, 256, 256, 256};
    const int Ns[9] = {256, 256, 256, 256, 256, 256, 256, 256, 4};
    const int Tn[9] = {8, 8, 8, 8, 8, 8, 8, 8, 1};
    const float* ws[9] = {w1, w2, w3, w4, w5, w6, w7, w8, w9};

    int g = blockIdx.x * blockDim.x + threadIdx.x;
    int tile = g >> 6, lane = g & 63;
    if (tile >= 976) return;
    int layer = 0;
    while (tile >= tileStart[layer + 1]) layer++;
    int t = tile - tileStart[layer];
    int tn = Tn[layer];
    int kt = t / tn, nt = t - kt * tn;
    int k0 = kt * 16 + (lane >> 5) * 8;
    int n = nt * 32 + (lane & 31);
    const float* w = ws[layer];
    int K = Ks[layer], N = Ns[layer];
    _Float16 v[8];
#pragma unroll
    for (int j = 0; j < 8; j++) {
        int k = k0 + j;
        v[j] = (k < K && n < N) ? (_Float16)w[k * N + n] : (_Float16)0.f;
    }
    *(half8*)(dst + (size_t)tile * 512 + lane * 8) = *(half8*)v;
}

// A-fragment read: single base + immediate offset (halfs): s*2048 + mi*256.
// FROMX selects the x-buffer (XOFF = first x kstep) at compile time.
template <bool FROMX, int XOFF>
__device__ __forceinline__ half8 rdA(const _Float16* aB, const _Float16* xB,
                                     int s, int mi) {
    if (FROMX) return *(const half8*)(xB + (s - XOFF) * 2048 + mi * 256);
    return *(const half8*)(aB + s * 2048 + mi * 256);
}

// Two k-steps: 8 ds_read_b128 + 16 MFMA, W frags already resident (no copies).
template <bool FROMX, int XOFF>
__device__ __forceinline__ void two_steps(const _Float16* aB, const _Float16* xB,
                                          int ks,
                                          half8 wa0, half8 wa1,   // step ks  (n0,n1)
                                          half8 wb0, half8 wb1,   // step ks+1
                                          floatx16 (&acc)[4][2]) {
    half8 a0 = rdA<FROMX, XOFF>(aB, xB, ks, 0);
    half8 a1 = rdA<FROMX, XOFF>(aB, xB, ks, 1);
    half8 a2 = rdA<FROMX, XOFF>(aB, xB, ks, 2);
    half8 a3 = rdA<FROMX, XOFF>(aB, xB, ks, 3);
    half8 b0 = rdA<FROMX, XOFF>(aB, xB, ks + 1, 0);
    half8 b1 = rdA<FROMX, XOFF>(aB, xB, ks + 1, 1);
    half8 b2 = rdA<FROMX, XOFF>(aB, xB, ks + 1, 2);
    half8 b3 = rdA<FROMX, XOFF>(aB, xB, ks + 1, 3);
    __builtin_amdgcn_s_setprio(1);
    acc[0][0] = __builtin_amdgcn_mfma_f32_32x32x16_f16(wa0, a0, acc[0][0], 0, 0, 0);
    acc[0][1] = __builtin_amdgcn_mfma_f32_32x32x16_f16(wa1, a0, acc[0][1], 0, 0, 0);
    acc[1][0] = __builtin_amdgcn_mfma_f32_32x32x16_f16(wa0, a1, acc[1][0], 0, 0, 0);
    acc[1][1] = __builtin_amdgcn_mfma_f32_32x32x16_f16(wa1, a1, acc[1][1], 0, 0, 0);
    acc[2][0] = __builtin_amdgcn_mfma_f32_32x32x16_f16(wa0, a2, acc[2][0], 0, 0, 0);
    acc[2][1] = __builtin_amdgcn_mfma_f32_32x32x16_f16(wa1, a2, acc[2][1], 0, 0, 0);
    acc[3][0] = __builtin_amdgcn_mfma_f32_32x32x16_f16(wa0, a3, acc[3][0], 0, 0, 0);
    acc[3][1] = __builtin_amdgcn_mfma_f32_32x32x16_f16(wa1, a3, acc[3][1], 0, 0, 0);
    acc[0][0] = __builtin_amdgcn_mfma_f32_32x32x16_f16(wb0, b0, acc[0][0], 0, 0, 0);
    acc[0][1] = __builtin_amdgcn_mfma_f32_32x32x16_f16(wb1, b0, acc[0][1], 0, 0, 0);
    acc[1][0] = __builtin_amdgcn_mfma_f32_32x32x16_f16(wb0, b1, acc[1][0], 0, 0, 0);
    acc[1][1] = __builtin_amdgcn_mfma_f32_32x32x16_f16(wb1, b1, acc[1][1], 0, 0, 0);
    acc[2][0] = __builtin_amdgcn_mfma_f32_32x32x16_f16(wb0, b2, acc[2][0], 0, 0, 0);
    acc[2][1] = __builtin_amdgcn_mfma_f32_32x32x16_f16(wb1, b2, acc[2][1], 0, 0, 0);
    acc[3][0] = __builtin_amdgcn_mfma_f32_32x32x16_f16(wb0, b3, acc[3][0], 0, 0, 0);
    acc[3][1] = __builtin_amdgcn_mfma_f32_32x32x16_f16(wb1, b3, acc[3][1], 0, 0, 0);
    __builtin_amdgcn_s_setprio(0);
}

// One k-step (odd tails): 4 ds_read_b128 + 8 MFMA.
template <bool FROMX, int XOFF>
__device__ __forceinline__ void one_step(const _Float16* aB, const _Float16* xB,
                                         int ks, half8 wa0, half8 wa1,
                                         floatx16 (&acc)[4][2]) {
    half8 a0 = rdA<FROMX, XOFF>(aB, xB, ks, 0);
    half8 a1 = rdA<FROMX, XOFF>(aB, xB, ks, 1);
    half8 a2 = rdA<FROMX, XOFF>(aB, xB, ks, 2);
    half8 a3 = rdA<FROMX, XOFF>(aB, xB, ks, 3);
    __builtin_amdgcn_s_setprio(1);
    acc[0][0] = __builtin_amdgcn_mfma_f32_32x32x16_f16(wa0, a0, acc[0][0], 0, 0, 0);
    acc[0][1] = __builtin_amdgcn_mfma_f32_32x32x16_f16(wa1, a0, acc[0][1], 0, 0, 0);
    acc[1][0] = __builtin_amdgcn_mfma_f32_32x32x16_f16(wa0, a1, acc[1][0], 0, 0, 0);
    acc[1][1] = __builtin_amdgcn_mfma_f32_32x32x16_f16(wa1, a1, acc[1][1], 0, 0, 0);
    acc[2][0] = __builtin_amdgcn_mfma_f32_32x32x16_f16(wa0, a2, acc[2][0], 0, 0, 0);
    acc[2][1] = __builtin_amdgcn_mfma_f32_32x32x16_f16(wa1, a2, acc[2][1], 0, 0, 0);
    acc[3][0] = __builtin_amdgcn_mfma_f32_32x32x16_f16(wa0, a3, acc[3][0], 0, 0, 0);
    acc[3][1] = __builtin_amdgcn_mfma_f32_32x32x16_f16(wa1, a3, acc[3][1], 0, 0, 0);
    __builtin_amdgcn_s_setprio(0);
}

// ---------------------------------------------------------------------------
// One fused layer: C(128x256) = relu(A(128xK) @ W + b), in-place LDS->LDS.
// Wave tile 128x64; 2-deep no-copy W ring; A via immediate-offset ds reads.
// AMODE 0: act only. 1: tail ksteps >= KS0 from x (L5 skip; KS0 == KMAIN).
// 2: entirely x (L1).
// ---------------------------------------------------------------------------
template <int KT, int AMODE, int KS0>
__device__ __forceinline__ void layerT(const _Float16* abuf,
                                       const _Float16* __restrict__ xbuf,
                                       const half8* __restrict__ wq,
                                       const float* __restrict__ bias,
                                       _Float16* obuf,
                                       int lane, int wave) {
    constexpr int KTAIL = (KT % 4 == 0) ? 4 : (KT % 4);
    constexpr int KMAIN = KT - KTAIL;
    static_assert(KTAIL == 4 || KTAIL == 3, "tail must be 3 or 4 ksteps");
    static_assert(AMODE != 1 || KS0 == KMAIN, "L5 x-switch must align with tail");
    constexpr bool MX = (AMODE == 2);   // main loop reads x?
    constexpr bool TX = (AMODE != 0);   // tail reads x?
    constexpr int TOFF = (AMODE == 1) ? KS0 : 0;

    const int l31 = lane & 31, lhi = lane >> 5;
    const _Float16* aBase = abuf + lhi * 1024 + l31 * 8;
    const _Float16* xBase = xbuf + lhi * 1024 + l31 * 8;
    // W frag (kstep ks, n-tile wave*2+ni): wl[ks*512 + ni*64]
    const half8* wl = wq + (wave * 2) * 64 + lane;

    // Bias -> acc init: acc element g*4+r is channel wave*64 + ni*32 + lhi*4 + g*8 + r.
    floatx16 acc[4][2];
#pragma unroll
    for (int ni = 0; ni < 2; ni++) {
        floatx16 t;
#pragma unroll
        for (int g = 0; g < 4; g++) {
            floatx4 b = *(const floatx4*)(bias + wave * 64 + ni * 32 + g * 8 + lhi * 4);
#pragma unroll
            for (int r = 0; r < 4; r++) t[g * 4 + r] = b[r];
        }
#pragma unroll
        for (int mi = 0; mi < 4; mi++) acc[mi][ni] = t;
    }

    // 2-deep W ring, no register copies (R16-proven structure).
    half8 w0a = wl[0], w0b = wl[64];
    half8 w1a = wl[512], w1b = wl[512 + 64];
#pragma unroll 1
    for (int ks = 0; ks < KMAIN; ks += 4) {
        half8 w2a = wl[(ks + 2) * 512], w2b = wl[(ks + 2) * 512 + 64];
        half8 w3a = wl[(ks + 3) * 512], w3b = wl[(ks + 3) * 512 + 64];
        two_steps<MX, 0>(aBase, xBase, ks, w0a, w0b, w1a, w1b, acc);
        w0a = wl[(ks + 4) * 512]; w0b = wl[(ks + 4) * 512 + 64];
        w1a = wl[(ks + 5) * 512]; w1b = wl[(ks + 5) * 512 + 64];
        two_steps<MX, 0>(aBase, xBase, ks + 2, w2a, w2b, w3a, w3b, acc);
    }
    if constexpr (KTAIL == 4) {
        half8 w2a = wl[(KT - 2) * 512], w2b = wl[(KT - 2) * 512 + 64];
        half8 w3a = wl[(KT - 1) * 512], w3b = wl[(KT - 1) * 512 + 64];
        two_steps<TX, TOFF>(aBase, xBase, KMAIN, w0a, w0b, w1a, w1b, acc);
        two_steps<TX, TOFF>(aBase, xBase, KMAIN + 2, w2a, w2b, w3a, w3b, acc);
    } else {  // KTAIL == 3
        half8 w2a = wl[(KT - 1) * 512], w2b = wl[(KT - 1) * 512 + 64];
        two_steps<TX, TOFF>(aBase, xBase, KMAIN, w0a, w0b, w1a, w1b, acc);
        one_step<TX, TOFF>(aBase, xBase, KMAIN + 2, w2a, w2b, acc);
    }

    // relu + fp16 cvt into regs BEFORE the barrier (shrink serialized tail).
    half4v hv[4][2][4];
#pragma unroll
    for (int mi = 0; mi < 4; mi++)
#pragma unroll
        for (int ni = 0; ni < 2; ni++)
#pragma unroll
            for (int g = 0; g < 4; g++) {
                half4v h;
#pragma unroll
                for (int r = 0; r < 4; r++) {
                    float v = acc[mi][ni][g * 4 + r];
                    v = v > 0.f ? v : 0.f;
                    h[r] = (_Float16)v;
                }
                hv[mi][ni][g] = h;
            }

    // In-place safety barrier: all waves' act-reads complete before any write.
    if (AMODE != 2) __syncthreads();
    // col = wave*64 + ni*32 + g*8 + lhi*4 + r -> chunk = wave*8 + ni*4 + g,
    // inner = lhi*4 + r; row = mi*32 + l31.
#pragma unroll
    for (int mi = 0; mi < 4; mi++) {
        _Float16* ob = obuf + (mi * 32 + l31) * 8 + lhi * 4;
#pragma unroll
        for (int ni = 0; ni < 2; ni++)
#pragma unroll
            for (int g = 0; g < 4; g++)
                *(half4v*)(ob + (wave * 8 + ni * 4 + g) * 1024) = hv[mi][ni][g];
    }
}

// Layer 9 (swapped): 256 -> 4 (N padded to 32). Each of 4 waves takes one
// 32-row m-frag; dual accumulators break the serial MFMA chain. Fully
// unrolled (16 W loads + 16 ds_reads scheduled freely by the compiler).
__device__ __forceinline__ void layer9T(const _Float16* abuf,
                                        const half8* __restrict__ wq,
                                        const float* __restrict__ b9,
                                        float* __restrict__ out, long r0,
                                        int lane, int wave) {
    const int l31 = lane & 31, lhi = lane >> 5;
    const _Float16* aBase = abuf + lhi * 1024 + (wave * 32 + l31) * 8;
    floatx16 acc_e = {}, acc_o = {};
    const half8* wl = wq + lane;
#pragma unroll
    for (int ks = 0; ks < 16; ks += 2) {
        half8 we = wl[ks * 64], wo = wl[(ks + 1) * 64];
        half8 ae = *(const half8*)(aBase + ks * 2048);
        half8 ao = *(const half8*)(aBase + (ks + 1) * 2048);
        acc_e = __builtin_amdgcn_mfma_f32_32x32x16_f16(we, ae, acc_e, 0, 0, 0);
        acc_o = __builtin_amdgcn_mfma_f32_32x32x16_f16(wo, ao, acc_o, 0, 0, 0);
    }
    if (lhi == 0) {
        floatx4 b4 = *(const floatx4*)(b9);
        floatx4 o;
#pragma unroll
        for (int r = 0; r < 4; r++) o[r] = acc_e[r] + acc_o[r] + b4[r];
        *(floatx4*)(out + (r0 + wave * 32 + l31) * 4) = o;
    }
}

__global__ __launch_bounds__(256, 2) void mlp_fused(
    const float* __restrict__ x, const _Float16* __restrict__ wpk,
    const float* __restrict__ b1, const float* __restrict__ b2,
    const float* __restrict__ b3, const float* __restrict__ b4,
    const float* __restrict__ b5, const float* __restrict__ b6,
    const float* __restrict__ b7, const float* __restrict__ b8,
    const float* __restrict__ b9, float* __restrict__ out) {
    // act 128x256 fp16 (64 KiB, in-place) + x 128x48 (12 KiB) = 76 KiB;
    // 4-wave blocks; 2 blocks/CU = 8 waves/CU = 2 waves/SIMD (256-reg cap).
    __shared__ _Float16 lds[128 * 256 + 128 * 48];
    _Float16* buf = lds;
    _Float16* xbuf = lds + 128 * 256;
    const int tid = threadIdx.x;
    const int lane = tid & 63, wave = tid >> 6;
    const long r0 = (long)blockIdx.x * 128;

    // Stage x (chunk-major): zero pad cols (39..47), fill cols 0..38.
    for (int i = tid; i < 128 * 9; i += 256) {
        int row = i / 9, col = 39 + (i - row * 9);
        xbuf[cmaj(row, col)] = (_Float16)0.f;
    }
    for (int i = tid; i < 128 * 39; i += 256) {
        int row = i / 39, col = i - row * 39;
        xbuf[cmaj(row, col)] = (_Float16)x[r0 * 39 + i];  // contiguous 4992 floats
    }
    __syncthreads();

    const half8* wp = (const half8*)wpk;  // tile = 64 half8 (1 KB)
    const half8* w1q = wp + (size_t)0 * 64;
    const half8* w2q = wp + (size_t)32 * 64;
    const half8* w3q = wp + (size_t)160 * 64;
    const half8* w4q = wp + (size_t)288 * 64;
    const half8* w5q = wp + (size_t)416 * 64;
    const half8* w6q = wp + (size_t)576 * 64;
    const half8* w7q = wp + (size_t)704 * 64;
    const half8* w8q = wp + (size_t)832 * 64;
    const half8* w9q = wp + (size_t)960 * 64;

    layerT<3, 2, 0>(xbuf, xbuf, w1q, b1, buf, lane, wave);   // x -> buf (K=48)
    __syncthreads();
    layerT<16, 0, 0>(buf, xbuf, w2q, b2, buf, lane, wave);
    __syncthreads();
    layerT<16, 0, 0>(buf, xbuf, w3q, b3, buf, lane, wave);
    __syncthreads();
    layerT<16, 0, 0>(buf, xbuf, w4q, b4, buf, lane, wave);
    __syncthreads();
    layerT<19, 1, 16>(buf, xbuf, w5q, b5, buf, lane, wave);  // [h|x] skip, K=304
    __syncthreads();
    layerT<16, 0, 0>(buf, xbuf, w6q, b6, buf, lane, wave);
    __syncthreads();
    layerT<16, 0, 0>(buf, xbuf, w7q, b7, buf, lane, wave);
    __syncthreads();
    layerT<16, 0, 0>(buf, xbuf, w8q, b8, buf, lane, wave);
    __syncthreads();
    layer9T(buf, w9q, b9, out, r0, lane, wave);
}

extern "C" void kernel_launch(void* const* d_in, const int* in_sizes, int n_in,
                              void* d_out, int out_size, void* d_ws, size_t ws_size,
                              hipStream_t stream) {
    const float* x = (const float*)d_in[0];
    const float* w[9];
    const float* b[9];
    for (int i = 0; i < 9; i++) {
        w[i] = (const float*)d_in[1 + 2 * i];
        b[i] = (const float*)d_in[2 + 2 * i];
    }
    _Float16* wpk = (_Float16*)d_ws;  // 999424 B

    pack_w32<<<244, 256, 0, stream>>>(w[0], w[1], w[2], w[3], w[4], w[5], w[6], w[7], w[8], wpk);
    mlp_fused<<<262144 / 128, 256, 0, stream>>>(x, wpk, b[0], b[1], b[2], b[3], b[4],
                                                b[5], b[6], b[7], b[8], (float*)d_out);
}